// Round 2
// baseline (44.269 us; speedup 1.0000x reference)
//
#include <hip/hip_runtime.h>
#include <hip/hip_bf16.h>

#define HH 64
#define WW 128
#define HW 8192   // H*W
#define CC 256

typedef unsigned uv4 __attribute__((ext_vector_type(4)));

__device__ __forceinline__ float bf_lo(unsigned u) { return __uint_as_float(u << 16); }
__device__ __forceinline__ float bf_hi(unsigned u) { return __uint_as_float(u & 0xffff0000u); }

// Fused transpose: [C, HW] fp32 -> [HW, C] bf16 for both fmaps.
// blockIdx.z: 0 -> fmap1 (scale 1/16 folded), 1 -> fmap2.
__global__ __launch_bounds__(256) void transpose_both(
    const float* __restrict__ f1, const float* __restrict__ f2,
    __hip_bfloat16* __restrict__ f1T, __hip_bfloat16* __restrict__ f2T)
{
  const float* src = blockIdx.z ? f2 : f1;
  __hip_bfloat16* dst = blockIdx.z ? f2T : f1T;
  float scale = blockIdx.z ? 1.0f : 0.0625f;

  __shared__ float tile[32][33];
  int tx = threadIdx.x, ty = threadIdx.y;       // block (32, 8)
  int pos0 = blockIdx.x * 32, c0 = blockIdx.y * 32;
#pragma unroll
  for (int r = 0; r < 4; ++r)
    tile[ty + r * 8][tx] =
        __builtin_nontemporal_load(&src[(size_t)(c0 + ty + r * 8) * HW + pos0 + tx]) * scale;
  __syncthreads();
#pragma unroll
  for (int r = 0; r < 4; ++r)
    dst[(size_t)(pos0 + ty + r * 8) * CC + c0 + tx] =
        __float2bfloat16(tile[tx][ty + r * 8]);
}

// One wave per pixel. 4 groups of 16 lanes; each group computes one neighbor
// dot per iteration (lane q covers channels [q*16, q*16+16) -> contiguous 32B).
// Only f2T is reused across waves -> everything else is non-temporal so f2T
// stays resident in per-XCD L2 (it is exactly 4 MiB).
__global__ __launch_bounds__(256) void corr_main(
    const float* __restrict__ coords,
    const unsigned* __restrict__ f1T,   // [HW][128] uints (256 bf16)
    const unsigned* __restrict__ f2T,
    float* __restrict__ out)
{
  int tid  = threadIdx.x;
  int wave = tid >> 6;
  int lane = tid & 63;
  int g    = lane >> 4;   // group 0..3
  int q    = lane & 15;   // lane in group
  int p    = blockIdx.x * 4 + wave;   // pixel, grid = 2048 -> p < 8192

  float x = __builtin_nontemporal_load(&coords[p]);
  float y = __builtin_nontemporal_load(&coords[HW + p]);
  float x0f = floorf(x), y0f = floorf(y);
  float fx = x - x0f, fy = y - y0f;
  int ix0 = (int)x0f - 4;
  int iy0 = (int)y0f - 4;

  // preload f1 channels [q*16, q*16+16) as fp32 (scale 1/16 already folded)
  const uv4* f1p = (const uv4*)(f1T + (size_t)p * 128 + q * 8);
  uv4 A0 = __builtin_nontemporal_load(f1p);
  uv4 A1 = __builtin_nontemporal_load(f1p + 1);
  float f1v[16] = { bf_lo(A0.x), bf_hi(A0.x), bf_lo(A0.y), bf_hi(A0.y),
                    bf_lo(A0.z), bf_hi(A0.z), bf_lo(A0.w), bf_hi(A0.w),
                    bf_lo(A1.x), bf_hi(A1.x), bf_lo(A1.y), bf_hi(A1.y),
                    bf_lo(A1.z), bf_hi(A1.z), bf_lo(A1.w), bf_hi(A1.w) };

  __shared__ float dots[4][100];

#pragma unroll 2
  for (int t = 0; t < 25; ++t) {
    int n = t * 4 + g;            // patch index, n = u*10 + v
    int u = n / 10;               // x-offset index 0..9
    int v = n - u * 10;           // y-offset index 0..9
    int gx = ix0 + u, gy = iy0 + v;
    bool valid = (gx >= 0) && (gx < WW) && (gy >= 0) && (gy < HH);
    int pos = valid ? (gy * WW + gx) : 0;
    const uv4* f2p = (const uv4*)(f2T + (size_t)pos * 128 + q * 8);
    uv4 B0 = f2p[0], B1 = f2p[1];
    float acc =      bf_lo(B0.x) * f1v[0];
    acc = fmaf(bf_hi(B0.x), f1v[1],  acc);
    acc = fmaf(bf_lo(B0.y), f1v[2],  acc);
    acc = fmaf(bf_hi(B0.y), f1v[3],  acc);
    acc = fmaf(bf_lo(B0.z), f1v[4],  acc);
    acc = fmaf(bf_hi(B0.z), f1v[5],  acc);
    acc = fmaf(bf_lo(B0.w), f1v[6],  acc);
    acc = fmaf(bf_hi(B0.w), f1v[7],  acc);
    acc = fmaf(bf_lo(B1.x), f1v[8],  acc);
    acc = fmaf(bf_hi(B1.x), f1v[9],  acc);
    acc = fmaf(bf_lo(B1.y), f1v[10], acc);
    acc = fmaf(bf_hi(B1.y), f1v[11], acc);
    acc = fmaf(bf_lo(B1.z), f1v[12], acc);
    acc = fmaf(bf_hi(B1.z), f1v[13], acc);
    acc = fmaf(bf_lo(B1.w), f1v[14], acc);
    acc = fmaf(bf_hi(B1.w), f1v[15], acc);
    // reduce across the 16-lane group
    acc += __shfl_xor(acc, 1);
    acc += __shfl_xor(acc, 2);
    acc += __shfl_xor(acc, 4);
    acc += __shfl_xor(acc, 8);
    if (q == 0) dots[wave][n] = valid ? acc : 0.0f;
  }

  __syncthreads();

  float wx1 = fx, wx0 = 1.0f - fx, wy1 = fy, wy0 = 1.0f - fy;
  for (int k = lane; k < 81; k += 64) {
    int i = k / 9;          // x-offset index (dx = i-4)
    int j = k - i * 9;      // y-offset index (dy = j-4)
    float d00 = dots[wave][i * 10 + j];
    float d10 = dots[wave][(i + 1) * 10 + j];
    float d01 = dots[wave][i * 10 + j + 1];
    float d11 = dots[wave][(i + 1) * 10 + j + 1];
    float o = wy0 * fmaf(wx1, d10, wx0 * d00) + wy1 * fmaf(wx1, d11, wx0 * d01);
    __builtin_nontemporal_store(o, &out[(size_t)k * HW + p]);
  }
}

// Correct-but-slow fallback if workspace is too small (reads original layout).
__global__ __launch_bounds__(64) void corr_fallback(
    const float* __restrict__ coords, const float* __restrict__ f1,
    const float* __restrict__ f2, float* __restrict__ out)
{
  int lane = threadIdx.x;
  int p = blockIdx.x;
  float x = coords[p], y = coords[HW + p];
  float x0f = floorf(x), y0f = floorf(y);
  float fx = x - x0f, fy = y - y0f;
  int ix0 = (int)x0f - 4, iy0 = (int)y0f - 4;
  float f1v[4];
#pragma unroll
  for (int k = 0; k < 4; ++k)
    f1v[k] = f1[(size_t)(lane + 64 * k) * HW + p] * 0.0625f;
  __shared__ float dots[100];
  for (int n = 0; n < 100; ++n) {
    int u = n / 10, v = n - u * 10;
    int gx = ix0 + u, gy = iy0 + v;
    bool valid = (gx >= 0) && (gx < WW) && (gy >= 0) && (gy < HH);
    int pos = valid ? (gy * WW + gx) : 0;
    float acc = 0.0f;
#pragma unroll
    for (int k = 0; k < 4; ++k)
      acc = fmaf(f1v[k], f2[(size_t)(lane + 64 * k) * HW + pos], acc);
    acc += __shfl_xor(acc, 1);
    acc += __shfl_xor(acc, 2);
    acc += __shfl_xor(acc, 4);
    acc += __shfl_xor(acc, 8);
    acc += __shfl_xor(acc, 16);
    acc += __shfl_xor(acc, 32);
    if (lane == 0) dots[n] = valid ? acc : 0.0f;
  }
  __syncthreads();
  float wx1 = fx, wx0 = 1.0f - fx, wy1 = fy, wy0 = 1.0f - fy;
  for (int k = lane; k < 81; k += 64) {
    int i = k / 9, j = k - i * 9;
    float d00 = dots[i * 10 + j];
    float d10 = dots[(i + 1) * 10 + j];
    float d01 = dots[i * 10 + j + 1];
    float d11 = dots[(i + 1) * 10 + j + 1];
    float o = wy0 * fmaf(wx1, d10, wx0 * d00) + wy1 * fmaf(wx1, d11, wx0 * d01);
    out[(size_t)k * HW + p] = o;
  }
}

extern "C" void kernel_launch(void* const* d_in, const int* in_sizes, int n_in,
                              void* d_out, int out_size, void* d_ws, size_t ws_size,
                              hipStream_t stream) {
  const float* fmap1  = (const float*)d_in[0];
  const float* fmap2  = (const float*)d_in[1];
  const float* coords = (const float*)d_in[2];
  float* out = (float*)d_out;

  size_t need = (size_t)HW * CC * sizeof(__hip_bfloat16) * 2;  // 8 MB
  if (ws_size >= need) {
    __hip_bfloat16* f1T = (__hip_bfloat16*)d_ws;
    __hip_bfloat16* f2T = f1T + (size_t)HW * CC;
    dim3 tb(32, 8), tg(HW / 32, CC / 32, 2);
    hipLaunchKernelGGL(transpose_both, tg, tb, 0, stream, fmap1, fmap2, f1T, f2T);
    corr_main<<<dim3(HW / 4), dim3(256), 0, stream>>>(
        coords, (const unsigned*)f1T, (const unsigned*)f2T, out);
  } else {
    corr_fallback<<<dim3(HW), dim3(64), 0, stream>>>(coords, fmap1, fmap2, out);
  }
}

// Round 3
// 43.140 us; speedup vs baseline: 1.0262x; 1.0262x over previous
//
#include <hip/hip_runtime.h>
#include <hip/hip_bf16.h>

#define HH 64
#define WW 128
#define HW 8192   // H*W
#define CC 256

typedef unsigned uv4 __attribute__((ext_vector_type(4)));
typedef unsigned uv2 __attribute__((ext_vector_type(2)));

__device__ __forceinline__ float bf_lo(unsigned u) { return __uint_as_float(u << 16); }
__device__ __forceinline__ float bf_hi(unsigned u) { return __uint_as_float(u & 0xffff0000u); }

__device__ __forceinline__ int dot4(unsigned a, unsigned b, int c) {
#if __has_builtin(__builtin_amdgcn_sdot4)
  return __builtin_amdgcn_sdot4((int)a, (int)b, c, false);
#else
  int r = c;
  r += ((int)(a << 24) >> 24) * ((int)(b << 24) >> 24);
  r += ((int)(a << 16) >> 24) * ((int)(b << 16) >> 24);
  r += ((int)(a <<  8) >> 24) * ((int)(b <<  8) >> 24);
  r += ((int)a >> 24)         * ((int)b >> 24);
  return r;
#endif
}

// Fused transpose: [C, HW] fp32 -> [HW, C] bf16 for both fmaps.
// blockIdx.z: 0 -> fmap1 (scale 1/16 folded), 1 -> fmap2.
__global__ __launch_bounds__(256) void transpose_both(
    const float* __restrict__ f1, const float* __restrict__ f2,
    __hip_bfloat16* __restrict__ f1T, __hip_bfloat16* __restrict__ f2T)
{
  const float* src = blockIdx.z ? f2 : f1;
  __hip_bfloat16* dst = blockIdx.z ? f2T : f1T;
  float scale = blockIdx.z ? 1.0f : 0.0625f;

  __shared__ float tile[32][33];
  int tx = threadIdx.x, ty = threadIdx.y;       // block (32, 8)
  int pos0 = blockIdx.x * 32, c0 = blockIdx.y * 32;
#pragma unroll
  for (int r = 0; r < 4; ++r)
    tile[ty + r * 8][tx] =
        __builtin_nontemporal_load(&src[(size_t)(c0 + ty + r * 8) * HW + pos0 + tx]) * scale;
  __syncthreads();
#pragma unroll
  for (int r = 0; r < 4; ++r)
    dst[(size_t)(pos0 + ty + r * 8) * CC + c0 + tx] =
        __float2bfloat16(tile[tx][ty + r * 8]);
}

// Per-position symmetric int8 quantization of the bf16 rows.
// One 32-lane half-wave per position: 8 bf16 per lane, shfl-max, pack 8 int8.
__global__ __launch_bounds__(256) void quant_rows(
    const uv4* __restrict__ f1T, const uv4* __restrict__ f2T,   // [HW][32] uint4
    uv2* __restrict__ f1q, uv2* __restrict__ f2q,               // [HW][32] uint2
    float* __restrict__ s1, float* __restrict__ s2)
{
  const uv4* srcT = blockIdx.z ? f2T : f1T;
  uv2* dq = blockIdx.z ? f2q : f1q;
  float* ds = blockIdx.z ? s2 : s1;

  int tid = threadIdx.x;
  int w = tid >> 6, lane = tid & 63;
  int h = lane & 31;
  int pos = blockIdx.x * 8 + w * 2 + (lane >> 5);

  uv4 B = __builtin_nontemporal_load(&srcT[(size_t)pos * 32 + h]);
  float v[8] = { bf_lo(B.x), bf_hi(B.x), bf_lo(B.y), bf_hi(B.y),
                 bf_lo(B.z), bf_hi(B.z), bf_lo(B.w), bf_hi(B.w) };
  float m = fabsf(v[0]);
#pragma unroll
  for (int i = 1; i < 8; ++i) m = fmaxf(m, fabsf(v[i]));
  m = fmaxf(m, __shfl_xor(m, 1));
  m = fmaxf(m, __shfl_xor(m, 2));
  m = fmaxf(m, __shfl_xor(m, 4));
  m = fmaxf(m, __shfl_xor(m, 8));
  m = fmaxf(m, __shfl_xor(m, 16));   // masks <=16 keep the two 32-halves separate

  float inv = (m > 0.0f) ? 127.0f / m : 0.0f;
  if (h == 0) ds[pos] = m * (1.0f / 127.0f);

  unsigned lo = 0, hi = 0;
#pragma unroll
  for (int i = 0; i < 4; ++i) {
    int qi = (int)rintf(v[i] * inv);
    lo |= ((unsigned)(qi & 0xff)) << (8 * i);
  }
#pragma unroll
  for (int i = 0; i < 4; ++i) {
    int qi = (int)rintf(v[4 + i] * inv);
    hi |= ((unsigned)(qi & 0xff)) << (8 * i);
  }
  uv2 o; o.x = lo; o.y = hi;
  dq[(size_t)pos * 32 + h] = o;   // plain store: keep f2q L2-resident
}

// One wave per pixel; 4 groups of 16 lanes, one neighbor dot per group-iter.
// Lane q covers channels [16q,16q+16) = one dwordx4 of packed int8.
__global__ __launch_bounds__(256) void corr_int8(
    const float* __restrict__ coords,
    const uv4* __restrict__ f1q,   // [HW][16] uint4 (256 int8)
    const uv4* __restrict__ f2q,
    const float* __restrict__ s1,
    const float* __restrict__ s2,
    float* __restrict__ out)
{
  int tid  = threadIdx.x;
  int wave = tid >> 6;
  int lane = tid & 63;
  int g    = lane >> 4;
  int q    = lane & 15;
  int p    = blockIdx.x * 4 + wave;

  float x = __builtin_nontemporal_load(&coords[p]);
  float y = __builtin_nontemporal_load(&coords[HW + p]);
  float x0f = floorf(x), y0f = floorf(y);
  float fx = x - x0f, fy = y - y0f;
  int ix0 = (int)x0f - 4;
  int iy0 = (int)y0f - 4;

  float s1v = s1[p];   // includes the 1/16 fold
  uv4 A = __builtin_nontemporal_load(&f1q[(size_t)p * 16 + q]);

  __shared__ float dots[4][100];

#pragma unroll 5
  for (int t = 0; t < 25; ++t) {
    int n = t * 4 + g;            // patch index, n = u*10 + v
    int u = n / 10;               // x-offset index 0..9
    int v = n - u * 10;           // y-offset index 0..9
    int gx = ix0 + u, gy = iy0 + v;
    bool valid = (gx >= 0) && (gx < WW) && (gy >= 0) && (gy < HH);
    int pos = valid ? (gy * WW + gx) : 0;
    uv4 B = f2q[(size_t)pos * 16 + q];
    float s2v = s2[pos];
    int acc = dot4(A.x, B.x, dot4(A.y, B.y, dot4(A.z, B.z, dot4(A.w, B.w, 0))));
    acc += __shfl_xor(acc, 1);
    acc += __shfl_xor(acc, 2);
    acc += __shfl_xor(acc, 4);
    acc += __shfl_xor(acc, 8);
    if (q == 0) dots[wave][n] = valid ? (float)acc * s1v * s2v : 0.0f;
  }

  __syncthreads();

  float wx1 = fx, wx0 = 1.0f - fx, wy1 = fy, wy0 = 1.0f - fy;
  for (int k = lane; k < 81; k += 64) {
    int i = k / 9;          // x-offset index (dx = i-4)
    int j = k - i * 9;      // y-offset index (dy = j-4)
    float d00 = dots[wave][i * 10 + j];
    float d10 = dots[wave][(i + 1) * 10 + j];
    float d01 = dots[wave][i * 10 + j + 1];
    float d11 = dots[wave][(i + 1) * 10 + j + 1];
    float o = wy0 * fmaf(wx1, d10, wx0 * d00) + wy1 * fmaf(wx1, d11, wx0 * d01);
    __builtin_nontemporal_store(o, &out[(size_t)k * HW + p]);
  }
}

// Correct-but-slow fallback if workspace is too small (reads original layout).
__global__ __launch_bounds__(64) void corr_fallback(
    const float* __restrict__ coords, const float* __restrict__ f1,
    const float* __restrict__ f2, float* __restrict__ out)
{
  int lane = threadIdx.x;
  int p = blockIdx.x;
  float x = coords[p], y = coords[HW + p];
  float x0f = floorf(x), y0f = floorf(y);
  float fx = x - x0f, fy = y - y0f;
  int ix0 = (int)x0f - 4, iy0 = (int)y0f - 4;
  float f1v[4];
#pragma unroll
  for (int k = 0; k < 4; ++k)
    f1v[k] = f1[(size_t)(lane + 64 * k) * HW + p] * 0.0625f;
  __shared__ float dots[100];
  for (int n = 0; n < 100; ++n) {
    int u = n / 10, v = n - u * 10;
    int gx = ix0 + u, gy = iy0 + v;
    bool valid = (gx >= 0) && (gx < WW) && (gy >= 0) && (gy < HH);
    int pos = valid ? (gy * WW + gx) : 0;
    float acc = 0.0f;
#pragma unroll
    for (int k = 0; k < 4; ++k)
      acc = fmaf(f1v[k], f2[(size_t)(lane + 64 * k) * HW + pos], acc);
    acc += __shfl_xor(acc, 1);
    acc += __shfl_xor(acc, 2);
    acc += __shfl_xor(acc, 4);
    acc += __shfl_xor(acc, 8);
    acc += __shfl_xor(acc, 16);
    acc += __shfl_xor(acc, 32);
    if (lane == 0) dots[n] = valid ? acc : 0.0f;
  }
  __syncthreads();
  float wx1 = fx, wx0 = 1.0f - fx, wy1 = fy, wy0 = 1.0f - fy;
  for (int k = lane; k < 81; k += 64) {
    int i = k / 9, j = k - i * 9;
    float d00 = dots[i * 10 + j];
    float d10 = dots[(i + 1) * 10 + j];
    float d01 = dots[i * 10 + j + 1];
    float d11 = dots[(i + 1) * 10 + j + 1];
    float o = wy0 * fmaf(wx1, d10, wx0 * d00) + wy1 * fmaf(wx1, d11, wx0 * d01);
    out[(size_t)k * HW + p] = o;
  }
}

extern "C" void kernel_launch(void* const* d_in, const int* in_sizes, int n_in,
                              void* d_out, int out_size, void* d_ws, size_t ws_size,
                              hipStream_t stream) {
  const float* fmap1  = (const float*)d_in[0];
  const float* fmap2  = (const float*)d_in[1];
  const float* coords = (const float*)d_in[2];
  float* out = (float*)d_out;

  // workspace layout (sizes in bytes)
  const size_t szT = (size_t)HW * CC * 2;   // 4 MB per bf16 transpose
  const size_t szQ = (size_t)HW * CC;       // 2 MB per int8 copy
  const size_t szS = (size_t)HW * 4;        // 32 KB per scale array
  const size_t need = 2 * szT + 2 * szQ + 2 * szS;

  if (ws_size >= need) {
    char* w = (char*)d_ws;
    __hip_bfloat16* f1T = (__hip_bfloat16*)w;
    __hip_bfloat16* f2T = (__hip_bfloat16*)(w + szT);
    unsigned char*  f1q = (unsigned char*)(w + 2 * szT);
    unsigned char*  f2q = (unsigned char*)(w + 2 * szT + szQ);
    float*          s1  = (float*)(w + 2 * szT + 2 * szQ);
    float*          s2  = (float*)(w + 2 * szT + 2 * szQ + szS);

    dim3 tb(32, 8), tg(HW / 32, CC / 32, 2);
    hipLaunchKernelGGL(transpose_both, tg, tb, 0, stream, fmap1, fmap2, f1T, f2T);
    quant_rows<<<dim3(HW / 8, 1, 2), dim3(256), 0, stream>>>(
        (const uv4*)f1T, (const uv4*)f2T, (uv2*)f1q, (uv2*)f2q, s1, s2);
    corr_int8<<<dim3(HW / 4), dim3(256), 0, stream>>>(
        coords, (const uv4*)f1q, (const uv4*)f2q, s1, s2, out);
  } else {
    corr_fallback<<<dim3(HW), dim3(64), 0, stream>>>(coords, fmap1, fmap2, out);
  }
}